// Round 2
// baseline (266.504 us; speedup 1.0000x reference)
//
#include <hip/hip_runtime.h>
#include <hip/hip_bf16.h>
#include <math.h>
#include <type_traits>

#define FDIM 128     // in/hid feature dim
#define ODIM 40      // output classes

typedef __attribute__((ext_vector_type(8))) short bf16x8;
typedef __attribute__((ext_vector_type(4))) float f32x4;

// ---- bf16 pack/unpack helpers (manual, RNE) --------------------------------
__device__ __forceinline__ float bf_lo(unsigned v) { return __uint_as_float(v << 16); }
__device__ __forceinline__ float bf_hi(unsigned v) { return __uint_as_float(v & 0xFFFF0000u); }
__device__ __forceinline__ unsigned f2bf(float f) {   // round-to-nearest-even
    unsigned u = __float_as_uint(f);
    return (u + 0x7FFFu + ((u >> 16) & 1u)) >> 16;
}

// ---------------------------------------------------------------------------
// 1) count in-degrees (dst atomics) + convert W1/W2 -> Wt bf16 (fused)
// ---------------------------------------------------------------------------
__global__ void count_conv_k(const int* __restrict__ dst, int* __restrict__ count, int E,
                             const float* __restrict__ W1, const float* __restrict__ W2,
                             unsigned short* __restrict__ Wt1, unsigned short* __restrict__ Wt2) {
    int e = blockIdx.x * 256 + threadIdx.x;
    if (e < E) atomicAdd(&count[dst[e]], 1);
    if (e < 2 * 16384) {                       // first 128 blocks also transpose weights
        const float* W = (e < 16384) ? W1 : W2;
        unsigned short* Wt = (e < 16384) ? Wt1 : Wt2;
        int j = e & 16383;
        int k = j >> 7, n = j & 127;
        Wt[n * 128 + k] = (unsigned short)f2bf(W[k * 128 + n]);
    }
}

// ---------------------------------------------------------------------------
// 2) single-pass decoupled-lookback exclusive scan over count[N] (1024/block)
// ---------------------------------------------------------------------------
#define FLG_AGG (1ull << 62)
#define FLG_INC (2ull << 62)
__global__ __launch_bounds__(256) void scan_lookback_k(
        const int* __restrict__ count, unsigned long long* __restrict__ states,
        int* __restrict__ rowptr, int* __restrict__ cursor,
        float* __restrict__ dinv, int n, int nblocks) {
    __shared__ int ts[256];
    __shared__ int s_prefix;
    const int b = blockIdx.x, tid = threadIdx.x;
    const int base = b * 1024 + tid * 4;
    int c[4];
    int s = 0;
#pragma unroll
    for (int j = 0; j < 4; ++j) {
        int i = base + j;
        c[j] = (i < n) ? count[i] : 0;
        s += c[j];
    }
    ts[tid] = s;
    __syncthreads();
    for (int off = 1; off < 256; off <<= 1) {   // Hillis-Steele inclusive
        int v = (tid >= off) ? ts[tid - off] : 0;
        __syncthreads();
        ts[tid] += v;
        __syncthreads();
    }
    const int total = ts[255];
    if (tid == 0) {
        if (b == 0) {
            __hip_atomic_store(&states[0], FLG_INC | (unsigned long long)total,
                               __ATOMIC_RELAXED, __HIP_MEMORY_SCOPE_AGENT);
            s_prefix = 0;
        } else {
            __hip_atomic_store(&states[b], FLG_AGG | (unsigned long long)total,
                               __ATOMIC_RELAXED, __HIP_MEMORY_SCOPE_AGENT);
            int prefix = 0;
            int j = b - 1;
            while (true) {
                unsigned long long v = __hip_atomic_load(&states[j], __ATOMIC_RELAXED,
                                                         __HIP_MEMORY_SCOPE_AGENT);
                unsigned long long f = v >> 62;
                if (f == 2ull) { prefix += (int)(v & 0xFFFFFFFFull); break; }
                if (f == 1ull) { prefix += (int)(v & 0xFFFFFFFFull); --j; }
                else __builtin_amdgcn_s_sleep(1);
            }
            __hip_atomic_store(&states[b], FLG_INC | (unsigned long long)(prefix + total),
                               __ATOMIC_RELAXED, __HIP_MEMORY_SCOPE_AGENT);
            s_prefix = prefix;
        }
    }
    __syncthreads();
    int excl = s_prefix + ts[tid] - s;
#pragma unroll
    for (int j = 0; j < 4; ++j) {
        int i = base + j;
        if (i < n) {
            rowptr[i] = excl;
            cursor[i] = excl;
            dinv[i] = rsqrtf((float)(c[j] + 1));
        }
        excl += c[j];
    }
    if (b == nblocks - 1 && tid == 255) rowptr[n] = s_prefix + total;
}

// ---------------------------------------------------------------------------
// 3) fill CSR: src ids grouped by dst
// ---------------------------------------------------------------------------
__global__ void fill_csr_k(const int* __restrict__ src, const int* __restrict__ dst,
                           int* __restrict__ cursor, int* __restrict__ csr_src, int E) {
    int e = blockIdx.x * blockDim.x + threadIdx.x;
    if (e < E) {
        int d = dst[e];
        int p = atomicAdd(&cursor[d], 1);
        csr_src[p] = src[e];
    }
}

// ---------------------------------------------------------------------------
// 4) MFMA GEMM: Cb[M,128](bf16) = (A[M,128] @ W) * dinv[row]
// ---------------------------------------------------------------------------
template <typename AT>
__global__ __launch_bounds__(256) void mfma_gemm_k(const AT* __restrict__ A,
                                                   const unsigned short* __restrict__ Wt,
                                                   const float* __restrict__ dinv,
                                                   unsigned short* __restrict__ Cb, int M) {
    __shared__ unsigned short As[64][136];   // row stride 272 B = 4 banks mod 32
    __shared__ unsigned short Bs[128][136];

    const int tid = threadIdx.x;
    const int row0 = blockIdx.x * 64;

    // ---- stage A (64 x 128) ----
    if constexpr (std::is_same_v<AT, float>) {
#pragma unroll
        for (int i = 0; i < 8; ++i) {        // 64 rows * 32 float4 = 2048
            int fidx = i * 256 + tid;
            int r = fidx >> 5, kq = fidx & 31;
            float4 v = make_float4(0.f, 0.f, 0.f, 0.f);
            int grow = row0 + r;
            if (grow < M) v = *(const float4*)&A[(size_t)grow * 128 + kq * 4];
            unsigned lo = f2bf(v.x) | (f2bf(v.y) << 16);
            unsigned hi = f2bf(v.z) | (f2bf(v.w) << 16);
            *(uint2*)&As[r][kq * 4] = make_uint2(lo, hi);
        }
    } else {
#pragma unroll
        for (int i = 0; i < 4; ++i) {        // 64 rows * 16 uint4 = 1024
            int fidx = i * 256 + tid;
            int r = fidx >> 4, kq = fidx & 15;
            uint4 v = make_uint4(0, 0, 0, 0);
            int grow = row0 + r;
            if (grow < M) v = *(const uint4*)&A[(size_t)grow * 128 + kq * 8];
            *(uint4*)&As[r][kq * 8] = v;
        }
    }
    // ---- stage B (128 x 128) ----
#pragma unroll
    for (int i = 0; i < 8; ++i) {            // 128 rows * 16 uint4 = 2048
        int fidx = i * 256 + tid;
        int r = fidx >> 4, kq = fidx & 15;
        *(uint4*)&Bs[r][kq * 8] = *(const uint4*)&Wt[(size_t)r * 128 + kq * 8];
    }
    __syncthreads();

    // ---- compute ----
    const int lane = tid & 63;
    const int wv = tid >> 6;       // wave 0..3 -> cols wv*32 .. +31
    const int n0 = wv * 32;
    const int mrow = lane & 15;
    const int quad = lane >> 4;

    f32x4 acc[4][2];
#pragma unroll
    for (int mt = 0; mt < 4; ++mt)
#pragma unroll
        for (int nt = 0; nt < 2; ++nt) acc[mt][nt] = (f32x4){0.f, 0.f, 0.f, 0.f};

#pragma unroll
    for (int kk = 0; kk < 128; kk += 32) {
        int ko = kk + quad * 8;
        bf16x8 af[4], bfr[2];
#pragma unroll
        for (int mt = 0; mt < 4; ++mt) af[mt] = *(const bf16x8*)&As[mt * 16 + mrow][ko];
#pragma unroll
        for (int nt = 0; nt < 2; ++nt) bfr[nt] = *(const bf16x8*)&Bs[n0 + nt * 16 + mrow][ko];
#pragma unroll
        for (int mt = 0; mt < 4; ++mt)
#pragma unroll
            for (int nt = 0; nt < 2; ++nt)
                acc[mt][nt] = __builtin_amdgcn_mfma_f32_16x16x32_bf16(af[mt], bfr[nt], acc[mt][nt], 0, 0, 0);
    }

    // ---- epilogue: C layout col=lane&15, row=quad*4+reg ----
#pragma unroll
    for (int mt = 0; mt < 4; ++mt) {
#pragma unroll
        for (int reg = 0; reg < 4; ++reg) {
            int grow = row0 + mt * 16 + quad * 4 + reg;
            if (grow < M) {
                float sc = dinv[grow];
#pragma unroll
                for (int nt = 0; nt < 2; ++nt) {
                    int col = n0 + nt * 16 + mrow;
                    Cb[(size_t)grow * 128 + col] = (unsigned short)f2bf(acc[mt][nt][reg] * sc);
                }
            }
        }
    }
}

// ---------------------------------------------------------------------------
// shared gather body: accumulate bf16x2 rows of g over a CSR range.
// Index prefetch: the next batch of 8 CSR indices is loaded while the current
// 8 row-gathers are in flight, removing the scalar-load latency from the
// per-iteration critical path. Tail paths identical to the verified version
// (accumulation order preserved bit-for-bit).
// ---------------------------------------------------------------------------
__device__ __forceinline__ void gather_accum(const unsigned* __restrict__ g,
                                             const int* __restrict__ csr_src,
                                             int e, int end, int c,
                                             float& ax, float& ay) {
    int idx[8];
    if (e + 8 <= end) {
#pragma unroll
        for (int t = 0; t < 8; ++t) idx[t] = csr_src[e + t];
    }
    while (e + 8 <= end) {
        unsigned v0 = g[(size_t)idx[0] * 64 + c], v1 = g[(size_t)idx[1] * 64 + c];
        unsigned v2 = g[(size_t)idx[2] * 64 + c], v3 = g[(size_t)idx[3] * 64 + c];
        unsigned v4 = g[(size_t)idx[4] * 64 + c], v5 = g[(size_t)idx[5] * 64 + c];
        unsigned v6 = g[(size_t)idx[6] * 64 + c], v7 = g[(size_t)idx[7] * 64 + c];
        int e2 = e + 8;
        if (e2 + 8 <= end) {
#pragma unroll
            for (int t = 0; t < 8; ++t) idx[t] = csr_src[e2 + t];
        }
        ax += (bf_lo(v0) + bf_lo(v1)) + (bf_lo(v2) + bf_lo(v3))
            + (bf_lo(v4) + bf_lo(v5)) + (bf_lo(v6) + bf_lo(v7));
        ay += (bf_hi(v0) + bf_hi(v1)) + (bf_hi(v2) + bf_hi(v3))
            + (bf_hi(v4) + bf_hi(v5)) + (bf_hi(v6) + bf_hi(v7));
        e = e2;
    }
    if (e + 3 < end) {                    // 4-wide mid tail (mean degree ~12)
        int s0 = csr_src[e], s1 = csr_src[e + 1], s2 = csr_src[e + 2], s3 = csr_src[e + 3];
        unsigned v0 = g[(size_t)s0 * 64 + c], v1 = g[(size_t)s1 * 64 + c];
        unsigned v2 = g[(size_t)s2 * 64 + c], v3 = g[(size_t)s3 * 64 + c];
        ax += (bf_lo(v0) + bf_lo(v1)) + (bf_lo(v2) + bf_lo(v3));
        ay += (bf_hi(v0) + bf_hi(v1)) + (bf_hi(v2) + bf_hi(v3));
        e += 4;
    }
    for (; e < end; ++e) {
        unsigned v = g[(size_t)csr_src[e] * 64 + c];
        ax += bf_lo(v);
        ay += bf_hi(v);
    }
}

// ---------------------------------------------------------------------------
// 5) layer-1 aggregate: out[d,:] = relu( dinv[d]*(g[d,:] + sum g[s,:]) + b )
//    4 waves / 256-thread block, one dst node per wave; bf16 output.
// ---------------------------------------------------------------------------
__global__ __launch_bounds__(256) void aggregate_k(const unsigned* __restrict__ g,
                                                   const float* __restrict__ dinv,
                                                   const int* __restrict__ rowptr,
                                                   const int* __restrict__ csr_src,
                                                   const float* __restrict__ bias,
                                                   unsigned* __restrict__ outb, int n) {
    const int wv = __builtin_amdgcn_readfirstlane(threadIdx.x >> 6);  // wave-uniform
    const int d = blockIdx.x * 4 + wv;
    if (d >= n) return;
    const int c = threadIdx.x & 63;       // lane: channels 2c, 2c+1
    unsigned self = g[(size_t)d * 64 + c];
    float ax = bf_lo(self), ay = bf_hi(self);
    gather_accum(g, csr_src, rowptr[d], rowptr[d + 1], c, ax, ay);
    float sc = dinv[d];
    float ox = fmaf(sc, ax, bias[2 * c]);
    float oy = fmaf(sc, ay, bias[2 * c + 1]);
    ox = fmaxf(ox, 0.f); oy = fmaxf(oy, 0.f);
    outb[(size_t)d * 64 + c] = f2bf(ox) | (f2bf(oy) << 16);
}

// ---------------------------------------------------------------------------
// 6) layer-2 aggregate + classifier head, fused.
//    8 waves / 512-thread block, one dst node per wave.
//    Per wave: finish x_emb row in registers -> write fp32 x_emb, park the row
//    in an LDS slot, then lane j<40 computes logit_j = x . Wl[:,j] + bl[j]
//    from LDS (Wl staged once per block = 20 KB), 64-lane shuffle softmax,
//    write log_softmax row. Removes the separate logits kernel + its
//    x_emb re-read entirely.
// ---------------------------------------------------------------------------
__global__ __launch_bounds__(512) void aggregate_head_k(
        const unsigned* __restrict__ g, const float* __restrict__ dinv,
        const int* __restrict__ rowptr, const int* __restrict__ csr_src,
        const float* __restrict__ bias, float2* __restrict__ xemb,
        const float* __restrict__ Wl, const float* __restrict__ bl,
        float* __restrict__ lsm, int n) {
    __shared__ float sWl[128 * 40];      // same layout as Wl: [k][j]
    __shared__ float sX[8][132];         // one x_emb row per wave (pad to 132)

    const int tid = threadIdx.x;
    // ---- stage Wl (20 KB) as straight float4 copy ----
#pragma unroll
    for (int i = 0; i < 3; ++i) {
        int f = i * 512 + tid;
        if (f < (128 * 40) / 4) ((float4*)sWl)[f] = ((const float4*)Wl)[f];
    }
    __syncthreads();

    const int wv = __builtin_amdgcn_readfirstlane(tid >> 6);  // wave-uniform
    const int d = blockIdx.x * 8 + wv;
    if (d >= n) return;
    const int c = tid & 63;               // lane: channels 2c, 2c+1
    unsigned self = g[(size_t)d * 64 + c];
    float ax = bf_lo(self), ay = bf_hi(self);
    gather_accum(g, csr_src, rowptr[d], rowptr[d + 1], c, ax, ay);
    float sc = dinv[d];
    float ox = fmaf(sc, ax, bias[2 * c]);
    float oy = fmaf(sc, ay, bias[2 * c + 1]);
    xemb[(size_t)d * 64 + c] = make_float2(ox, oy);   // fp32 x_emb output

    // park row in this wave's LDS slot (intra-wave producer/consumer only)
    *(float2*)&sX[wv][2 * c] = make_float2(ox, oy);
    asm volatile("s_waitcnt lgkmcnt(0)" ::: "memory");

    // ---- head: lane j < 40 owns one logit ----
    const int j = c;
    float acc;
    if (j < 40) {
        const float* xr = sX[wv];
        acc = 0.f;
#pragma unroll 16
        for (int k = 0; k < 128; ++k)     // sX read is wave-broadcast; sWl read
            acc = fmaf(xr[k], sWl[k * 40 + j], acc);  // is 40 lanes stride-40: ~2-way
        acc += bl[j];
    } else {
        acc = -INFINITY;                  // neutral for max; exp contribution 0
    }
    float m = acc;
#pragma unroll
    for (int off = 1; off < 64; off <<= 1) m = fmaxf(m, __shfl_xor(m, off));
    float p = (j < 40) ? expf(acc - m) : 0.f;
    float s = p;
#pragma unroll
    for (int off = 1; off < 64; off <<= 1) s += __shfl_xor(s, off);
    float lse = m + logf(s);
    if (j < 40) lsm[(size_t)d * 40 + j] = acc - lse;
}

// ---------------------------------------------------------------------------
// launch
// ---------------------------------------------------------------------------
extern "C" void kernel_launch(void* const* d_in, const int* in_sizes, int n_in,
                              void* d_out, int out_size, void* d_ws, size_t ws_size,
                              hipStream_t stream) {
    const float* x  = (const float*)d_in[0];
    const int*   ei = (const int*)d_in[1];
    const float* W1 = (const float*)d_in[2];
    const float* b1 = (const float*)d_in[3];
    const float* W2 = (const float*)d_in[4];
    const float* b2 = (const float*)d_in[5];
    const float* Wl = (const float*)d_in[6];
    const float* bl = (const float*)d_in[7];

    const int N = in_sizes[0] / FDIM;   // 50000
    const int E = in_sizes[1] / 2;      // 600000
    const int* src = ei;
    const int* dst = ei + E;

    float* out_lsm = (float*)d_out;                    // [N,40]
    float* x_emb   = (float*)d_out + (size_t)N * ODIM; // [N,128]

    // ---- workspace bump allocator (256 B aligned slots) ----
    char* w = (char*)d_ws;
    size_t off = 0;
    auto alloc = [&](size_t bytes) {
        void* p = w + off;
        off = (off + bytes + 255) & ~(size_t)255;
        return p;
    };
    int* count = (int*)alloc((size_t)N * 4);
    unsigned long long* states = (unsigned long long*)alloc(64 * 8);  // contiguous after count
    int* rowptr = (int*)alloc((size_t)(N + 1) * 4);
    int* cursor = (int*)alloc((size_t)N * 4);
    int* csr    = (int*)alloc((size_t)E * 4);
    float* dinv = (float*)alloc((size_t)N * 4);
    unsigned short* Wt1 = (unsigned short*)alloc(128 * 128 * 2);
    unsigned short* Wt2 = (unsigned short*)alloc(128 * 128 * 2);
    unsigned* bufA = (unsigned*)alloc((size_t)N * 64 * 4);
    unsigned* bufB = (unsigned*)alloc((size_t)N * 64 * 4);

    // zero count + states in ONE memset (they are adjacent slots)
    size_t zlen = ((char*)states - (char*)count) + 64 * 8;
    hipMemsetAsync(count, 0, zlen, stream);

    const int nsc = (N + 1023) / 1024;            // 49 scan blocks (<=64 states)
    count_conv_k<<<(E + 255) / 256, 256, 0, stream>>>(dst, count, E, W1, W2, Wt1, Wt2);
    scan_lookback_k<<<nsc, 256, 0, stream>>>(count, states, rowptr, cursor, dinv, N, nsc);
    fill_csr_k<<<(E + 255) / 256, 256, 0, stream>>>(src, dst, cursor, csr, E);

    int gblocks = (N + 63) / 64;
    // layer 1
    mfma_gemm_k<float><<<gblocks, 256, 0, stream>>>(x, Wt1, dinv, (unsigned short*)bufA, N);
    aggregate_k<<<(N + 3) / 4, 256, 0, stream>>>(bufA, dinv, rowptr, csr, b1, bufB, N);
    // layer 2 + fused classifier head
    mfma_gemm_k<unsigned short><<<gblocks, 256, 0, stream>>>(
        (const unsigned short*)bufB, Wt2, dinv, (unsigned short*)bufA, N);
    aggregate_head_k<<<(N + 7) / 8, 512, 0, stream>>>(
        bufA, dinv, rowptr, csr, b2, (float2*)x_emb, Wl, bl, out_lsm, N);
}